// Round 3
// baseline (266.551 us; speedup 1.0000x reference)
//
#include <hip/hip_runtime.h>
#include <hip/hip_bf16.h>

#define NN 4
#define LL 8192
#define HH 8
#define DD 64
#define NH 32                 // n*h combos
#define RS  (HH*DD)           // 512 floats per s row (all heads)
#define KV_ELEMS 4160         // 64x64 kv + ksum[64]
#define CCH 128               // C-kernel l-chunks per n -> 4*128 = 512 blocks (2/CU)

typedef __attribute__((ext_vector_type(8))) short bf16x8;   // 8 bf16 (4 VGPR)
typedef __attribute__((ext_vector_type(4))) float f32x4;

__device__ __forceinline__ float phi(float x) {
  // elu(x*temp) + 1 ; temp = 64^(-0.25)
  float t = x * 0.35355339059327373f;
  return t > 0.f ? t + 1.f : __expf(t);
}
__device__ __forceinline__ short f2bf(float x) {
  __hip_bfloat16 h = __float2bfloat16(x);                  // RN
  return (short)__builtin_bit_cast(unsigned short, h);
}
__device__ __forceinline__ float bf2f(short s) {
  __hip_bfloat16 h = __builtin_bit_cast(__hip_bfloat16, (unsigned short)s);
  return __bfloat162float(h);
}
__device__ __forceinline__ void split2(float x, short& hi, short& lo) {
  hi = f2bf(x);
  lo = f2bf(x - bf2f(hi));
}
#define MFMA16 __builtin_amdgcn_mfma_f32_16x16x32_bf16

// ---------------- Kernel A: partial kv[d][m] += phi(K)^T V, ALL 8 heads per block ----------
// v4: same h-fused contiguous-read structure as v3 (BW fix verified: 1.25->1.7
// TB/s) but sch=128 so the grid is 512 blocks -> 2 resident blocks/CU (v3 had
// exactly 1 block/CU = 18% occupancy; barriers idled the whole CU). Compute is
// fp32 VALU outer-product; thread owns (h = tid>>6, 8 d, 8 m) -> acc[8][8].
__global__ __launch_bounds__(512, 2) void kv_partial_kernel(
    const float* __restrict__ K, const float* __restrict__ V,
    float* __restrict__ part, int sch)
{
  const int n = blockIdx.x / sch, chunk = blockIdx.x % sch;
  const int tid = threadIdx.x;
  const int h  = tid >> 6;
  const int t6 = tid & 63;
  const int d0 = ((t6 >> 3) & 7) * 8;
  const int m0 = (t6 & 7) * 8;
  const int hc = h * 64;
  const int sr = tid >> 6, sc = (tid & 63) * 8;   // staging: row 0..7, col *8 floats
  const int rows_pb = LL / sch;
  const int nt = rows_pb / 8;                     // 8-row s-tiles

  const float* kbase = K + ((size_t)n * LL + (size_t)chunk * rows_pb) * RS;
  const float* vbase = V + ((size_t)n * LL + (size_t)chunk * rows_pb) * RS;

  __shared__ float kls[8][520];   // phi(K) rows, natural [s][h*64+d], pitch-pad
  __shared__ float vls[8][520];   // V rows

  float acc[8][8] = {};
  float ksacc[8] = {};            // ksum partial for this thread's 8 staged cols
  f32x4 kr[2], vr[2];

  auto loada = [&](int T) {
    const float* kp_ = kbase + ((size_t)T * 8 + sr) * RS + sc;
    const float* vp_ = vbase + ((size_t)T * 8 + sr) * RS + sc;
    kr[0] = *(const f32x4*)(kp_);     kr[1] = *(const f32x4*)(kp_ + 4);
    vr[0] = *(const f32x4*)(vp_);     vr[1] = *(const f32x4*)(vp_ + 4);
  };

  loada(0);
  for (int t = 0; t < nt; ++t) {
    // ---- stage: phi(K) + raw V, natural layout ----
    f32x4 kw0, kw1;
#pragma unroll
    for (int jj = 0; jj < 4; ++jj) {
      float f0 = phi(kr[0][jj]);
      float f1 = phi(kr[1][jj]);
      ksacc[jj]     += f0;
      ksacc[jj + 4] += f1;
      kw0[jj] = f0; kw1[jj] = f1;
    }
    *(f32x4*)&kls[sr][sc]     = kw0;
    *(f32x4*)&kls[sr][sc + 4] = kw1;
    *(f32x4*)&vls[sr][sc]     = vr[0];
    *(f32x4*)&vls[sr][sc + 4] = vr[1];
    __syncthreads();
    if (t + 1 < nt) loada(t + 1);        // overlap next loads with compute

    // ---- compute: 8 s-rows of outer product ----
#pragma unroll 2
    for (int s = 0; s < 8; ++s) {
      const f32x4 k0 = *(const f32x4*)&kls[s][hc + d0];
      const f32x4 k1 = *(const f32x4*)&kls[s][hc + d0 + 4];
      const f32x4 v0 = *(const f32x4*)&vls[s][hc + m0];
      const f32x4 v1 = *(const f32x4*)&vls[s][hc + m0 + 4];
#pragma unroll
      for (int i = 0; i < 4; ++i)
#pragma unroll
        for (int j = 0; j < 4; ++j) {
          acc[i][j]         = fmaf(k0[i], v0[j], acc[i][j]);
          acc[i][j + 4]     = fmaf(k0[i], v1[j], acc[i][j + 4]);
          acc[i + 4][j]     = fmaf(k1[i], v0[j], acc[i + 4][j]);
          acc[i + 4][j + 4] = fmaf(k1[i], v1[j], acc[i + 4][j + 4]);
        }
    }
    __syncthreads();
  }

  // ---- store partial kv (fp32, exact) ----
  float* po = part + ((size_t)blockIdx.x * 8 + h) * KV_ELEMS;
#pragma unroll
  for (int i = 0; i < 8; ++i) {
    f32x4 o0 = {acc[i][0], acc[i][1], acc[i][2], acc[i][3]};
    f32x4 o1 = {acc[i][4], acc[i][5], acc[i][6], acc[i][7]};
    *(f32x4*)&po[(d0 + i) * 64 + m0]     = o0;
    *(f32x4*)&po[(d0 + i) * 64 + m0 + 4] = o1;
  }

  // ---- ksum: per-thread col partials -> LDS reduce over the 8 staging rows ----
#pragma unroll
  for (int j = 0; j < 8; ++j) vls[sr][sc + j] = ksacc[j];
  __syncthreads();
  {
    float s = 0.f;
#pragma unroll
    for (int r = 0; r < 8; ++r) s += vls[r][tid];      // col = tid (0..511)
    part[((size_t)blockIdx.x * 8 + (tid >> 6)) * KV_ELEMS + 4096 + (tid & 63)] = s;
  }
}

// ---------------- Kernel B: reduce partials; emit kv m-major split hi/lo + ksum ----------------
__global__ __launch_bounds__(256) void kv_reduce_kernel(
    const float* __restrict__ part, short* __restrict__ kvh,
    short* __restrict__ kvl, float* __restrict__ ksum, int np)
{
  const int nh = blockIdx.x / 17;
  const int e  = (blockIdx.x % 17) * 256 + threadIdx.x;
  if (e >= KV_ELEMS) return;
  const int n = nh >> 3, hh = nh & 7;
  const float* pp = part + ((size_t)(n * np) * 8 + hh) * KV_ELEMS + e;
  float s = 0.f;
  for (int i = 0; i < np; ++i) s += pp[(size_t)i * 8 * KV_ELEMS];
  if (e < 4096) {
    const int d = e >> 6, m = e & 63;
    short hi, lo; split2(s, hi, lo);
    kvh[(size_t)nh * 4096 + m * 64 + d] = hi;     // m-major: C's B-frags read
    kvl[(size_t)nh * 4096 + m * 64 + d] = lo;     // contiguous d-runs
  } else {
    ksum[(size_t)nh * 64 + (e - 4096)] = s;
  }
}

// ---------------- Kernel C: out[l][m] = z_l * (phi(Q) . kv) via MFMA, ALL 8 heads/block ------
// v4: CCH=128 -> 512 blocks (2/CU; v3 had 1/CU). Block (512 thr) stages 16
// CONTIGUOUS 2KB Q rows (all heads) as bf16 hi/lo planes; wave w = head w reads
// d-contiguous A-frags (pitch 520 -> uniform slot spread), kv B-frags register-
// resident (64 VGPR). 2-tile register prefetch hides HBM latency.
__global__ __launch_bounds__(512, 2) void attn_out_kernel(
    const float* __restrict__ Q, const short* __restrict__ kvh,
    const short* __restrict__ kvl, const float* __restrict__ ksumg,
    float* __restrict__ out)
{
  const int n = blockIdx.x / CCH, chunk = blockIdx.x % CCH;
  const int tid = threadIdx.x;
  const int w = tid >> 6, lane = tid & 63;            // w = head
  const int q = lane >> 4, p = lane & 15;
  const int nh = n * 8 + w;
  const int rows_pb = LL / CCH;                       // 64
  const int nt = rows_pb / 16;                        // 4 tiles of 16 rows
  const int l_base = chunk * rows_pb;
  const int sr = tid >> 5, sc = (tid & 31) * 16;      // staging: row 0..15, col *16

  const float* qbase = Q + (size_t)n * LL * RS;

  __shared__ short qh[16][520];                       // phiQ hi plane, natural [l][h*64+d]
  __shared__ short ql[16][520];                       // phiQ lo plane

  // resident B frags for this wave's head: B[k=d][m], m-major kv
  bf16x8 bh[4][2], bl[4][2];
#pragma unroll
  for (int mt = 0; mt < 4; ++mt)
#pragma unroll
    for (int kst = 0; kst < 2; ++kst) {
      const size_t off = (size_t)nh * 4096 + (size_t)(mt * 16 + p) * 64 + kst * 32 + q * 8;
      bh[mt][kst] = *(const bf16x8*)(kvh + off);
      bl[mt][kst] = *(const bf16x8*)(kvl + off);
    }
  float ksr[2][8];
#pragma unroll
  for (int kst = 0; kst < 2; ++kst) {
    const float* kp = ksumg + (size_t)nh * 64 + kst * 32 + q * 8;
    f32x4 a = *(const f32x4*)(kp), b = *(const f32x4*)(kp + 4);
    ksr[kst][0]=a[0]; ksr[kst][1]=a[1]; ksr[kst][2]=a[2]; ksr[kst][3]=a[3];
    ksr[kst][4]=b[0]; ksr[kst][5]=b[1]; ksr[kst][6]=b[2]; ksr[kst][7]=b[3];
  }

  f32x4 qa[4], qb[4];
  auto loadq = [&](f32x4* R, int T) {
    const float* qp_ = qbase + (size_t)(l_base + T * 16 + sr) * RS + sc;
    R[0] = *(const f32x4*)(qp_);      R[1] = *(const f32x4*)(qp_ + 4);
    R[2] = *(const f32x4*)(qp_ + 8);  R[3] = *(const f32x4*)(qp_ + 12);
  };

  auto cbody = [&](const f32x4* R, int T) {
    // ---- stage: phi + hi/lo split, natural layout ----
    bf16x8 hv0, hv1, lv0, lv1;
#pragma unroll
    for (int r = 0; r < 2; ++r)
#pragma unroll
      for (int jj = 0; jj < 4; ++jj) {
        float f = phi(R[r][jj]);
        short hs, ls; split2(f, hs, ls);
        hv0[r * 4 + jj] = hs; lv0[r * 4 + jj] = ls;
      }
#pragma unroll
    for (int r = 0; r < 2; ++r)
#pragma unroll
      for (int jj = 0; jj < 4; ++jj) {
        float f = phi(R[r + 2][jj]);
        short hs, ls; split2(f, hs, ls);
        hv1[r * 4 + jj] = hs; lv1[r * 4 + jj] = ls;
      }
    *(bf16x8*)&qh[sr][sc]     = hv0;  *(bf16x8*)&qh[sr][sc + 8] = hv1;
    *(bf16x8*)&ql[sr][sc]     = lv0;  *(bf16x8*)&ql[sr][sc + 8] = lv1;
    __syncthreads();

    // ---- compute: A-frags (d-contiguous), z, 24 MFMA, scaled store ----
    f32x4 acc[4] = {};
    float zp = 0.f;
    bf16x8 ah[2], al[2];
#pragma unroll
    for (int kst = 0; kst < 2; ++kst) {
      const int cc = w * 64 + kst * 32 + q * 8;
      ah[kst] = *(const bf16x8*)&qh[p][cc];
      al[kst] = *(const bf16x8*)&ql[p][cc];
#pragma unroll
      for (int j = 0; j < 8; ++j)
        zp += (bf2f(ah[kst][j]) + bf2f(al[kst][j])) * ksr[kst][j];
    }
#pragma unroll
    for (int kst = 0; kst < 2; ++kst)
#pragma unroll
      for (int mt = 0; mt < 4; ++mt) {
        acc[mt] = MFMA16(ah[kst], bh[mt][kst], acc[mt], 0, 0, 0);
        acc[mt] = MFMA16(ah[kst], bl[mt][kst], acc[mt], 0, 0, 0);
        acc[mt] = MFMA16(al[kst], bh[mt][kst], acc[mt], 0, 0, 0);
      }
    zp += __shfl_xor(zp, 16, 64);
    zp += __shfl_xor(zp, 32, 64);
    const float z = 1.0f / (zp + 1e-6f);
    float zr[4];
#pragma unroll
    for (int r = 0; r < 4; ++r) zr[r] = __shfl(z, q * 4 + r, 64);

    const int l0 = l_base + T * 16;
#pragma unroll
    for (int mt = 0; mt < 4; ++mt)
#pragma unroll
      for (int r = 0; r < 4; ++r)
        out[((size_t)nh * LL + l0 + q * 4 + r) * DD + mt * 16 + p] = acc[mt][r] * zr[r];
    __syncthreads();
  };

  loadq(qa, 0);
  for (int t = 0; t < nt; t += 2) {        // nt = 4 (even)
    loadq(qb, t + 1);
    cbody(qa, t);
    if (t + 2 < nt) loadq(qa, t + 2);
    cbody(qb, t + 1);
  }
}

extern "C" void kernel_launch(void* const* d_in, const int* in_sizes, int n_in,
                              void* d_out, int out_size, void* d_ws, size_t ws_size,
                              hipStream_t stream)
{
  const float* Q = (const float*)d_in[0];
  const float* K = (const float*)d_in[1];
  const float* V = (const float*)d_in[2];
  float* out = (float*)d_out;

  int sch = 128;                                       // s-chunks per n -> 512 blocks
  while (sch > 4) {
    size_t need = (size_t)NN * sch * 8 * KV_ELEMS * 4  // partials
                + (size_t)NH * 4096 * 2 * 2            // kvh + kvl (bf16)
                + (size_t)NH * 64 * 4;                 // ksum
    if (need <= ws_size) break;
    sch >>= 1;
  }
  float* part = (float*)d_ws;
  short* kvh  = (short*)((char*)d_ws + (size_t)NN * sch * 8 * KV_ELEMS * 4);
  short* kvl  = kvh + (size_t)NH * 4096;
  float* ksum = (float*)(kvl + (size_t)NH * 4096);

  hipLaunchKernelGGL(kv_partial_kernel, dim3(NN * sch), dim3(512), 0, stream,
                     K, V, part, sch);
  hipLaunchKernelGGL(kv_reduce_kernel, dim3(NH * 17), dim3(256), 0, stream,
                     part, kvh, kvl, ksum, sch);
  hipLaunchKernelGGL(attn_out_kernel, dim3(NN * CCH), dim3(512), 0, stream,
                     Q, kvh, kvl, ksum, out);
}

// Round 4
// 247.149 us; speedup vs baseline: 1.0785x; 1.0785x over previous
//
#include <hip/hip_runtime.h>
#include <hip/hip_bf16.h>

#define NN 4
#define LL 8192
#define HH 8
#define DD 64
#define NH 32                 // n*h combos
#define RS  (HH*DD)           // 512 floats per s row (all heads)
#define KV_ELEMS 4160         // 64x64 kv + ksum[64]
#define CCH 128               // C-kernel l-chunks per n
#define TILE 16               // A-kernel s-rows per phase

typedef __attribute__((ext_vector_type(8))) short bf16x8;   // 8 bf16 (4 VGPR)
typedef __attribute__((ext_vector_type(4))) float f32x4;

__device__ __forceinline__ float phi(float x) {
  // elu(x*temp) + 1 ; temp = 64^(-0.25)
  float t = x * 0.35355339059327373f;
  return t > 0.f ? t + 1.f : __expf(t);
}
__device__ __forceinline__ short f2bf(float x) {
  __hip_bfloat16 h = __float2bfloat16(x);                  // RN
  return (short)__builtin_bit_cast(unsigned short, h);
}
__device__ __forceinline__ float bf2f(short s) {
  __hip_bfloat16 h = __builtin_bit_cast(__hip_bfloat16, (unsigned short)s);
  return __bfloat162float(h);
}
__device__ __forceinline__ void split2(float x, short& hi, short& lo) {
  hi = f2bf(x);
  lo = f2bf(x - bf2f(hi));
}
#define MFMA16 __builtin_amdgcn_mfma_f32_16x16x32_bf16

// ---------------- Kernel A: partial kv[d][m] += phi(K)^T V, ALL 8 heads per block ----------
// v5: barrier-count fix. v3/v4 ran 32 short phases with 2 barriers each; phase
// drain dominated (VALUBusy 25%, all pipes idle). Now: 16-row tiles, LDS
// DOUBLE-buffer, ONE barrier per tile (8 total). Phase t: issue global loads
// for t+1 (regs) || compute tile t from buf[t&1] || stage t+1 into buf[~t&1]
// (vmcnt covered by the 2048-cyc FMA phase) -> barrier. Reads stay h-fused
// contiguous 2KB rows (the verified DRAM-page fix). sch back to 64 (halves
// partial-write traffic that v4 added).
__global__ __launch_bounds__(512, 1) void kv_partial_kernel(
    const float* __restrict__ K, const float* __restrict__ V,
    float* __restrict__ part, int sch)
{
  const int n = blockIdx.x / sch, chunk = blockIdx.x % sch;
  const int tid = threadIdx.x;
  const int h  = tid >> 6;
  const int t6 = tid & 63;
  const int d0 = ((t6 >> 3) & 7) * 8;
  const int m0 = (t6 & 7) * 8;
  const int hc = h * 64;
  const int sr = tid >> 5;            // staging row 0..15
  const int sc = (tid & 31) * 16;     // staging col base (16 floats)
  const int rows_pb = LL / sch;       // 128 at sch=64
  const int nt = rows_pb / TILE;      // 8

  const float* kbase = K + ((size_t)n * LL + (size_t)chunk * rows_pb) * RS;
  const float* vbase = V + ((size_t)n * LL + (size_t)chunk * rows_pb) * RS;

  // [buf][K/V][s][col]; pitch 520 (pad) keeps compute reads conflict-free.
  __shared__ float lds[2][2][TILE][520];          // 133,120 B (1 block/CU)

  float acc[8][8] = {};
  float ksacc[16] = {};               // phiK partial sums for staged cols
  f32x4 kr[4], vr[4];

  auto loadregs = [&](int T) {
    const float* kp = kbase + ((size_t)T * TILE + sr) * RS + sc;
    const float* vp = vbase + ((size_t)T * TILE + sr) * RS + sc;
#pragma unroll
    for (int i = 0; i < 4; ++i) {
      kr[i] = *(const f32x4*)(kp + 4 * i);
      vr[i] = *(const f32x4*)(vp + 4 * i);
    }
  };
  auto stage = [&](int b) {
#pragma unroll
    for (int i = 0; i < 4; ++i) {
      f32x4 kw;
#pragma unroll
      for (int j = 0; j < 4; ++j) {
        float f = phi(kr[i][j]);
        ksacc[4 * i + j] += f;
        kw[j] = f;
      }
      *(f32x4*)&lds[b][0][sr][sc + 4 * i] = kw;
      *(f32x4*)&lds[b][1][sr][sc + 4 * i] = vr[i];
    }
  };

  loadregs(0);
  stage(0);
  __syncthreads();

  for (int t = 0; t < nt; ++t) {
    const int cur = t & 1;
    if (t + 1 < nt) loadregs(t + 1);            // issue early (T14)
#pragma unroll 2
    for (int s = 0; s < TILE; ++s) {
      const f32x4 k0 = *(const f32x4*)&lds[cur][0][s][hc + d0];
      const f32x4 k1 = *(const f32x4*)&lds[cur][0][s][hc + d0 + 4];
      const f32x4 v0 = *(const f32x4*)&lds[cur][1][s][hc + m0];
      const f32x4 v1 = *(const f32x4*)&lds[cur][1][s][hc + m0 + 4];
#pragma unroll
      for (int i = 0; i < 4; ++i)
#pragma unroll
        for (int j = 0; j < 4; ++j) {
          acc[i][j]         = fmaf(k0[i], v0[j], acc[i][j]);
          acc[i][j + 4]     = fmaf(k0[i], v1[j], acc[i][j + 4]);
          acc[i + 4][j]     = fmaf(k1[i], v0[j], acc[i + 4][j]);
          acc[i + 4][j + 4] = fmaf(k1[i], v1[j], acc[i + 4][j + 4]);
        }
    }
    if (t + 1 < nt) stage(cur ^ 1);             // write idle buffer (no race:
    __syncthreads();                            // cur^1 last read before prev barrier)
  }

  // ---- store partial kv (fp32, exact) ----
  float* po = part + ((size_t)blockIdx.x * 8 + h) * KV_ELEMS;
#pragma unroll
  for (int i = 0; i < 8; ++i) {
    f32x4 o0 = {acc[i][0], acc[i][1], acc[i][2], acc[i][3]};
    f32x4 o1 = {acc[i][4], acc[i][5], acc[i][6], acc[i][7]};
    *(f32x4*)&po[(d0 + i) * 64 + m0]     = o0;
    *(f32x4*)&po[(d0 + i) * 64 + m0 + 4] = o1;
  }

  // ---- ksum: per-thread col partials -> LDS reduce over the 16 staging rows ----
#pragma unroll
  for (int i = 0; i < 4; ++i) {
    f32x4 kw = {ksacc[4 * i], ksacc[4 * i + 1], ksacc[4 * i + 2], ksacc[4 * i + 3]};
    *(f32x4*)&lds[0][0][sr][sc + 4 * i] = kw;
  }
  __syncthreads();
  {
    float ssum = 0.f;
#pragma unroll
    for (int r = 0; r < TILE; ++r) ssum += lds[0][0][r][tid];     // col = tid
    part[((size_t)blockIdx.x * 8 + (tid >> 6)) * KV_ELEMS + 4096 + (tid & 63)] = ssum;
  }
}

// ---------------- Kernel B: reduce partials; emit kv m-major split hi/lo + ksum ----------------
__global__ __launch_bounds__(256) void kv_reduce_kernel(
    const float* __restrict__ part, short* __restrict__ kvh,
    short* __restrict__ kvl, float* __restrict__ ksum, int np)
{
  const int nh = blockIdx.x / 17;
  const int e  = (blockIdx.x % 17) * 256 + threadIdx.x;
  if (e >= KV_ELEMS) return;
  const int n = nh >> 3, hh = nh & 7;
  const float* pp = part + ((size_t)(n * np) * 8 + hh) * KV_ELEMS + e;
  float s = 0.f;
  for (int i = 0; i < np; ++i) s += pp[(size_t)i * 8 * KV_ELEMS];
  if (e < 4096) {
    const int d = e >> 6, m = e & 63;
    short hi, lo; split2(s, hi, lo);
    kvh[(size_t)nh * 4096 + m * 64 + d] = hi;     // m-major: C's B-frags read
    kvl[(size_t)nh * 4096 + m * 64 + d] = lo;     // contiguous d-runs
  } else {
    ksum[(size_t)nh * 64 + (e - 4096)] = s;
  }
}

// ---------------- Kernel C: out[l][m] = z_l * (phi(Q) . kv) via MFMA, ALL 8 heads/block ------
// unchanged from v4 (isolating the A change this round).
__global__ __launch_bounds__(512, 2) void attn_out_kernel(
    const float* __restrict__ Q, const short* __restrict__ kvh,
    const short* __restrict__ kvl, const float* __restrict__ ksumg,
    float* __restrict__ out)
{
  const int n = blockIdx.x / CCH, chunk = blockIdx.x % CCH;
  const int tid = threadIdx.x;
  const int w = tid >> 6, lane = tid & 63;            // w = head
  const int q = lane >> 4, p = lane & 15;
  const int nh = n * 8 + w;
  const int rows_pb = LL / CCH;                       // 64
  const int nt = rows_pb / 16;                        // 4 tiles of 16 rows
  const int l_base = chunk * rows_pb;
  const int sr = tid >> 5, sc = (tid & 31) * 16;      // staging: row 0..15, col *16

  const float* qbase = Q + (size_t)n * LL * RS;

  __shared__ short qh[16][520];                       // phiQ hi plane, natural [l][h*64+d]
  __shared__ short ql[16][520];                       // phiQ lo plane

  // resident B frags for this wave's head: B[k=d][m], m-major kv
  bf16x8 bh[4][2], bl[4][2];
#pragma unroll
  for (int mt = 0; mt < 4; ++mt)
#pragma unroll
    for (int kst = 0; kst < 2; ++kst) {
      const size_t off = (size_t)nh * 4096 + (size_t)(mt * 16 + p) * 64 + kst * 32 + q * 8;
      bh[mt][kst] = *(const bf16x8*)(kvh + off);
      bl[mt][kst] = *(const bf16x8*)(kvl + off);
    }
  float ksr[2][8];
#pragma unroll
  for (int kst = 0; kst < 2; ++kst) {
    const float* kp = ksumg + (size_t)nh * 64 + kst * 32 + q * 8;
    f32x4 a = *(const f32x4*)(kp), b = *(const f32x4*)(kp + 4);
    ksr[kst][0]=a[0]; ksr[kst][1]=a[1]; ksr[kst][2]=a[2]; ksr[kst][3]=a[3];
    ksr[kst][4]=b[0]; ksr[kst][5]=b[1]; ksr[kst][6]=b[2]; ksr[kst][7]=b[3];
  }

  f32x4 qa[4], qb[4];
  auto loadq = [&](f32x4* R, int T) {
    const float* qp_ = qbase + (size_t)(l_base + T * 16 + sr) * RS + sc;
    R[0] = *(const f32x4*)(qp_);      R[1] = *(const f32x4*)(qp_ + 4);
    R[2] = *(const f32x4*)(qp_ + 8);  R[3] = *(const f32x4*)(qp_ + 12);
  };

  auto cbody = [&](const f32x4* R, int T) {
    // ---- stage: phi + hi/lo split, natural layout ----
    bf16x8 hv0, hv1, lv0, lv1;
#pragma unroll
    for (int r = 0; r < 2; ++r)
#pragma unroll
      for (int jj = 0; jj < 4; ++jj) {
        float f = phi(R[r][jj]);
        short hs, ls; split2(f, hs, ls);
        hv0[r * 4 + jj] = hs; lv0[r * 4 + jj] = ls;
      }
#pragma unroll
    for (int r = 0; r < 2; ++r)
#pragma unroll
      for (int jj = 0; jj < 4; ++jj) {
        float f = phi(R[r + 2][jj]);
        short hs, ls; split2(f, hs, ls);
        hv1[r * 4 + jj] = hs; lv1[r * 4 + jj] = ls;
      }
    *(bf16x8*)&qh[sr][sc]     = hv0;  *(bf16x8*)&qh[sr][sc + 8] = hv1;
    *(bf16x8*)&ql[sr][sc]     = lv0;  *(bf16x8*)&ql[sr][sc + 8] = lv1;
    __syncthreads();

    // ---- compute: A-frags (d-contiguous), z, 24 MFMA, scaled store ----
    f32x4 acc[4] = {};
    float zp = 0.f;
    bf16x8 ah[2], al[2];
#pragma unroll
    for (int kst = 0; kst < 2; ++kst) {
      const int cc = w * 64 + kst * 32 + q * 8;
      ah[kst] = *(const bf16x8*)&qh[p][cc];
      al[kst] = *(const bf16x8*)&ql[p][cc];
#pragma unroll
      for (int j = 0; j < 8; ++j)
        zp += (bf2f(ah[kst][j]) + bf2f(al[kst][j])) * ksr[kst][j];
    }
#pragma unroll
    for (int kst = 0; kst < 2; ++kst)
#pragma unroll
      for (int mt = 0; mt < 4; ++mt) {
        acc[mt] = MFMA16(ah[kst], bh[mt][kst], acc[mt], 0, 0, 0);
        acc[mt] = MFMA16(ah[kst], bl[mt][kst], acc[mt], 0, 0, 0);
        acc[mt] = MFMA16(al[kst], bh[mt][kst], acc[mt], 0, 0, 0);
      }
    zp += __shfl_xor(zp, 16, 64);
    zp += __shfl_xor(zp, 32, 64);
    const float z = 1.0f / (zp + 1e-6f);
    float zr[4];
#pragma unroll
    for (int r = 0; r < 4; ++r) zr[r] = __shfl(z, q * 4 + r, 64);

    const int l0 = l_base + T * 16;
#pragma unroll
    for (int mt = 0; mt < 4; ++mt)
#pragma unroll
      for (int r = 0; r < 4; ++r)
        out[((size_t)nh * LL + l0 + q * 4 + r) * DD + mt * 16 + p] = acc[mt][r] * zr[r];
    __syncthreads();
  };

  loadq(qa, 0);
  for (int t = 0; t < nt; t += 2) {        // nt = 4 (even)
    loadq(qb, t + 1);
    cbody(qa, t);
    if (t + 2 < nt) loadq(qa, t + 2);
    cbody(qb, t + 1);
  }
}

extern "C" void kernel_launch(void* const* d_in, const int* in_sizes, int n_in,
                              void* d_out, int out_size, void* d_ws, size_t ws_size,
                              hipStream_t stream)
{
  const float* Q = (const float*)d_in[0];
  const float* K = (const float*)d_in[1];
  const float* V = (const float*)d_in[2];
  float* out = (float*)d_out;

  int sch = 64;                                        // s-chunks per n -> 256 blocks
  while (sch > 4) {
    size_t need = (size_t)NN * sch * 8 * KV_ELEMS * 4  // partials
                + (size_t)NH * 4096 * 2 * 2            // kvh + kvl (bf16)
                + (size_t)NH * 64 * 4;                 // ksum
    if (need <= ws_size) break;
    sch >>= 1;
  }
  float* part = (float*)d_ws;
  short* kvh  = (short*)((char*)d_ws + (size_t)NN * sch * 8 * KV_ELEMS * 4);
  short* kvl  = kvh + (size_t)NH * 4096;
  float* ksum = (float*)(kvl + (size_t)NH * 4096);

  hipLaunchKernelGGL(kv_partial_kernel, dim3(NN * sch), dim3(512), 0, stream,
                     K, V, part, sch);
  hipLaunchKernelGGL(kv_reduce_kernel, dim3(NH * 17), dim3(256), 0, stream,
                     part, kvh, kvl, ksum, sch);
  hipLaunchKernelGGL(attn_out_kernel, dim3(NN * CCH), dim3(512), 0, stream,
                     Q, kvh, kvl, ksum, out);
}

// Round 5
// 245.748 us; speedup vs baseline: 1.0847x; 1.0057x over previous
//
#include <hip/hip_runtime.h>
#include <hip/hip_bf16.h>

#define NN 4
#define LL 8192
#define HH 8
#define DD 64
#define NH 32                 // n*h combos
#define RS  (HH*DD)           // 512 floats per s row (all heads)
#define KV_ELEMS 4160         // 64x64 kv + ksum[64]
#define CCH 128               // C-kernel l-chunks per n

typedef __attribute__((ext_vector_type(8))) short bf16x8;   // 8 bf16 (4 VGPR)
typedef __attribute__((ext_vector_type(4))) float f32x4;

__device__ __forceinline__ float phi(float x) {
  // elu(x*temp) + 1 ; temp = 64^(-0.25)
  float t = x * 0.35355339059327373f;
  return t > 0.f ? t + 1.f : __expf(t);
}
__device__ __forceinline__ short f2bf(float x) {
  __hip_bfloat16 h = __float2bfloat16(x);                  // RN
  return (short)__builtin_bit_cast(unsigned short, h);
}
__device__ __forceinline__ float bf2f(short s) {
  __hip_bfloat16 h = __builtin_bit_cast(__hip_bfloat16, (unsigned short)s);
  return __bfloat162float(h);
}
__device__ __forceinline__ void split2(float x, short& hi, short& lo) {
  hi = f2bf(x);
  lo = f2bf(x - bf2f(hi));
}
#define MFMA16 __builtin_amdgcn_mfma_f32_16x16x32_bf16

// ---------------- Kernel A: partial kv[d][m] += phi(K)^T V via MFMA, h-fused ----------------
// v6: v5's fp32 route was LDS-pipe-bound (576 ds wave-insts/phase vs 7k cyc; VALU
// only 28%). Now the contraction runs on MFMA: stage bf16 hi/lo planes [col][32s]
// (pitch 32 shorts = 64B, NO pad) with k-order-preserving chunk swizzle
// pos = q ^ ((col ^ col>>2)&3): frag reads land on 8 bank-quads x 2 lanes =
// conflict-free; A(d-col) and B(m-col) use the same per-col k-permutation so the
// MFMA contraction is exact. Wave w = head w: full 64x64 kv, 48 split-mfma/step.
// Global reads stay h-fused contiguous 2KB rows. Same numerics as v1's A (passed
// at 2.4e-4).
__global__ __launch_bounds__(512, 1) void kv_partial_kernel(
    const float* __restrict__ K, const float* __restrict__ V,
    float* __restrict__ part, int sch)
{
  const int n = blockIdx.x / sch, chunk = blockIdx.x % sch;
  const int tid = threadIdx.x;
  const int w = tid >> 6, lane = tid & 63;    // w = head
  const int q = lane >> 4, p = lane & 15;
  const int cq = tid >> 7;                    // loader: 8-row chunk 0..3
  const int cg = tid & 127;                   // loader: col-group (4 cols)
  const int rows_pb = LL / sch;               // 128 at sch=64
  const int nsteps = rows_pb / 32;            // 4

  const float* kbase = K + ((size_t)n * LL + (size_t)chunk * rows_pb) * RS;
  const float* vbase = V + ((size_t)n * LL + (size_t)chunk * rows_pb) * RS;

  // planes: 0=K.hi 1=K.lo 2=V.hi 3=V.lo ; [col][32 s] chunk-swizzled; 128 KB
  __shared__ short pl[4][512 * 32];

  f32x4 acc[4][4] = {};                       // [dt][mt] 16x16 tiles
  float ksacc[4] = {0.f, 0.f, 0.f, 0.f};
  f32x4 kr[8], vr[8];

  auto loadregs = [&](int T) {
    const float* kp = kbase + (size_t)(T * 32 + cq * 8) * RS + 4 * cg;
    const float* vp = vbase + (size_t)(T * 32 + cq * 8) * RS + 4 * cg;
#pragma unroll
    for (int u = 0; u < 8; ++u) {
      kr[u] = *(const f32x4*)(kp + (size_t)u * RS);
      vr[u] = *(const f32x4*)(vp + (size_t)u * RS);
    }
  };
  auto cw = [&]() {                           // convert + swizzled transpose-write
#pragma unroll
    for (int j = 0; j < 4; ++j) {
      const int col = 4 * cg + j;
      const int pos = (cq ^ ((col ^ (col >> 2)) & 3)) * 8;
      bf16x8 kh, kl, vh, vl;
      float s = 0.f;
#pragma unroll
      for (int u = 0; u < 8; ++u) {
        float f = phi(kr[u][j]);
        s += f;
        short a, b;
        split2(f, a, b);          kh[u] = a; kl[u] = b;
        split2(vr[u][j], a, b);   vh[u] = a; vl[u] = b;
      }
      ksacc[j] += s;
      *(bf16x8*)&pl[0][col * 32 + pos] = kh;
      *(bf16x8*)&pl[1][col * 32 + pos] = kl;
      *(bf16x8*)&pl[2][col * 32 + pos] = vh;
      *(bf16x8*)&pl[3][col * 32 + pos] = vl;
    }
  };

  loadregs(0);
  for (int t = 0; t < nsteps; ++t) {
    cw();
    __syncthreads();
    if (t + 1 < nsteps) loadregs(t + 1);      // overlap HBM with MFMA phase

    bf16x8 ah[4], al[4], bh[4], bl[4];
#pragma unroll
    for (int dt = 0; dt < 4; ++dt) {
      const int col = w * 64 + dt * 16 + p;
      const int pos = (q ^ ((col ^ (col >> 2)) & 3)) * 8;
      ah[dt] = *(const bf16x8*)&pl[0][col * 32 + pos];
      al[dt] = *(const bf16x8*)&pl[1][col * 32 + pos];
      bh[dt] = *(const bf16x8*)&pl[2][col * 32 + pos];
      bl[dt] = *(const bf16x8*)&pl[3][col * 32 + pos];
    }
#pragma unroll
    for (int dt = 0; dt < 4; ++dt)
#pragma unroll
      for (int mt = 0; mt < 4; ++mt) {
        acc[dt][mt] = MFMA16(ah[dt], bh[mt], acc[dt][mt], 0, 0, 0);
        acc[dt][mt] = MFMA16(ah[dt], bl[mt], acc[dt][mt], 0, 0, 0);
        acc[dt][mt] = MFMA16(al[dt], bh[mt], acc[dt][mt], 0, 0, 0);
      }
    __syncthreads();
  }

  // ---- store partial kv: D layout col=lane&15, row=quad*4+reg ----
  float* po = part + ((size_t)blockIdx.x * 8 + w) * KV_ELEMS;
#pragma unroll
  for (int dt = 0; dt < 4; ++dt)
#pragma unroll
    for (int mt = 0; mt < 4; ++mt)
#pragma unroll
      for (int r = 0; r < 4; ++r)
        po[(dt * 16 + q * 4 + r) * 64 + mt * 16 + p] = acc[dt][mt][r];

  // ---- ksum: per-thread col partials -> LDS reduce over the 4 cq groups ----
  float* ksl = (float*)pl;                    // pl free after last barrier
  f32x4 kq = {ksacc[0], ksacc[1], ksacc[2], ksacc[3]};
  *(f32x4*)&ksl[cq * 520 + 4 * cg] = kq;
  __syncthreads();
  {
    float s = ksl[tid] + ksl[520 + tid] + ksl[1040 + tid] + ksl[1560 + tid];
    part[((size_t)blockIdx.x * 8 + (tid >> 6)) * KV_ELEMS + 4096 + (tid & 63)] = s;
  }
}

// ---------------- Kernel B: reduce partials; emit kv m-major split hi/lo + ksum ----------------
__global__ __launch_bounds__(256) void kv_reduce_kernel(
    const float* __restrict__ part, short* __restrict__ kvh,
    short* __restrict__ kvl, float* __restrict__ ksum, int np)
{
  const int nh = blockIdx.x / 17;
  const int e  = (blockIdx.x % 17) * 256 + threadIdx.x;
  if (e >= KV_ELEMS) return;
  const int n = nh >> 3, hh = nh & 7;
  const float* pp = part + ((size_t)(n * np) * 8 + hh) * KV_ELEMS + e;
  float s = 0.f;
  for (int i = 0; i < np; ++i) s += pp[(size_t)i * 8 * KV_ELEMS];
  if (e < 4096) {
    const int d = e >> 6, m = e & 63;
    short hi, lo; split2(s, hi, lo);
    kvh[(size_t)nh * 4096 + m * 64 + d] = hi;     // m-major: C's B-frags read
    kvl[(size_t)nh * 4096 + m * 64 + d] = lo;     // contiguous d-runs
  } else {
    ksum[(size_t)nh * 64 + (e - 4096)] = s;
  }
}

// ---------------- Kernel C: out[l][m] = z_l * (phi(Q) . kv) via MFMA, ALL 8 heads/block ------
// v6 tweak: post-read barrier hoisted above the MFMA/store tail so the next
// tile's staging overlaps compute (LDS untouched after frag reads).
__global__ __launch_bounds__(512, 2) void attn_out_kernel(
    const float* __restrict__ Q, const short* __restrict__ kvh,
    const short* __restrict__ kvl, const float* __restrict__ ksumg,
    float* __restrict__ out)
{
  const int n = blockIdx.x / CCH, chunk = blockIdx.x % CCH;
  const int tid = threadIdx.x;
  const int w = tid >> 6, lane = tid & 63;            // w = head
  const int q = lane >> 4, p = lane & 15;
  const int nh = n * 8 + w;
  const int rows_pb = LL / CCH;                       // 64
  const int nt = rows_pb / 16;                        // 4 tiles of 16 rows
  const int l_base = chunk * rows_pb;
  const int sr = tid >> 5, sc = (tid & 31) * 16;      // staging: row 0..15, col *16

  const float* qbase = Q + (size_t)n * LL * RS;

  __shared__ short qh[16][520];                       // phiQ hi plane, natural [l][h*64+d]
  __shared__ short ql[16][520];                       // phiQ lo plane

  // resident B frags for this wave's head: B[k=d][m], m-major kv
  bf16x8 bh[4][2], bl[4][2];
#pragma unroll
  for (int mt = 0; mt < 4; ++mt)
#pragma unroll
    for (int kst = 0; kst < 2; ++kst) {
      const size_t off = (size_t)nh * 4096 + (size_t)(mt * 16 + p) * 64 + kst * 32 + q * 8;
      bh[mt][kst] = *(const bf16x8*)(kvh + off);
      bl[mt][kst] = *(const bf16x8*)(kvl + off);
    }
  float ksr[2][8];
#pragma unroll
  for (int kst = 0; kst < 2; ++kst) {
    const float* kp = ksumg + (size_t)nh * 64 + kst * 32 + q * 8;
    f32x4 a = *(const f32x4*)(kp), b = *(const f32x4*)(kp + 4);
    ksr[kst][0]=a[0]; ksr[kst][1]=a[1]; ksr[kst][2]=a[2]; ksr[kst][3]=a[3];
    ksr[kst][4]=b[0]; ksr[kst][5]=b[1]; ksr[kst][6]=b[2]; ksr[kst][7]=b[3];
  }

  f32x4 qa[4], qb[4];
  auto loadq = [&](f32x4* R, int T) {
    const float* qp_ = qbase + (size_t)(l_base + T * 16 + sr) * RS + sc;
    R[0] = *(const f32x4*)(qp_);      R[1] = *(const f32x4*)(qp_ + 4);
    R[2] = *(const f32x4*)(qp_ + 8);  R[3] = *(const f32x4*)(qp_ + 12);
  };

  auto cbody = [&](const f32x4* R, int T) {
    // ---- stage: phi + hi/lo split, natural layout ----
    bf16x8 hv0, hv1, lv0, lv1;
#pragma unroll
    for (int r = 0; r < 2; ++r)
#pragma unroll
      for (int jj = 0; jj < 4; ++jj) {
        float f = phi(R[r][jj]);
        short hs, ls; split2(f, hs, ls);
        hv0[r * 4 + jj] = hs; lv0[r * 4 + jj] = ls;
      }
#pragma unroll
    for (int r = 0; r < 2; ++r)
#pragma unroll
      for (int jj = 0; jj < 4; ++jj) {
        float f = phi(R[r + 2][jj]);
        short hs, ls; split2(f, hs, ls);
        hv1[r * 4 + jj] = hs; lv1[r * 4 + jj] = ls;
      }
    *(bf16x8*)&qh[sr][sc]     = hv0;  *(bf16x8*)&qh[sr][sc + 8] = hv1;
    *(bf16x8*)&ql[sr][sc]     = lv0;  *(bf16x8*)&ql[sr][sc + 8] = lv1;
    __syncthreads();

    // ---- frag reads + z partial (LDS phase) ----
    f32x4 acc[4] = {};
    float zp = 0.f;
    bf16x8 ah[2], al[2];
#pragma unroll
    for (int kst = 0; kst < 2; ++kst) {
      const int cc = w * 64 + kst * 32 + q * 8;
      ah[kst] = *(const bf16x8*)&qh[p][cc];
      al[kst] = *(const bf16x8*)&ql[p][cc];
#pragma unroll
      for (int j = 0; j < 8; ++j)
        zp += (bf2f(ah[kst][j]) + bf2f(al[kst][j])) * ksr[kst][j];
    }
    __syncthreads();    // hoisted: LDS not used below -> next stage overlaps

    // ---- MFMA + z + scaled store (overlaps next tile's staging) ----
#pragma unroll
    for (int kst = 0; kst < 2; ++kst)
#pragma unroll
      for (int mt = 0; mt < 4; ++mt) {
        acc[mt] = MFMA16(ah[kst], bh[mt][kst], acc[mt], 0, 0, 0);
        acc[mt] = MFMA16(ah[kst], bl[mt][kst], acc[mt], 0, 0, 0);
        acc[mt] = MFMA16(al[kst], bh[mt][kst], acc[mt], 0, 0, 0);
      }
    zp += __shfl_xor(zp, 16, 64);
    zp += __shfl_xor(zp, 32, 64);
    const float z = 1.0f / (zp + 1e-6f);
    float zr[4];
#pragma unroll
    for (int r = 0; r < 4; ++r) zr[r] = __shfl(z, q * 4 + r, 64);

    const int l0 = l_base + T * 16;
#pragma unroll
    for (int mt = 0; mt < 4; ++mt)
#pragma unroll
      for (int r = 0; r < 4; ++r)
        out[((size_t)nh * LL + l0 + q * 4 + r) * DD + mt * 16 + p] = acc[mt][r] * zr[r];
  };

  loadq(qa, 0);
  for (int t = 0; t < nt; t += 2) {        // nt = 4 (even)
    loadq(qb, t + 1);
    cbody(qa, t);
    if (t + 2 < nt) loadq(qa, t + 2);
    cbody(qb, t + 1);
  }
}

extern "C" void kernel_launch(void* const* d_in, const int* in_sizes, int n_in,
                              void* d_out, int out_size, void* d_ws, size_t ws_size,
                              hipStream_t stream)
{
  const float* Q = (const float*)d_in[0];
  const float* K = (const float*)d_in[1];
  const float* V = (const float*)d_in[2];
  float* out = (float*)d_out;

  int sch = 64;                                        // s-chunks per n -> 256 blocks
  while (sch > 4) {
    size_t need = (size_t)NN * sch * 8 * KV_ELEMS * 4  // partials
                + (size_t)NH * 4096 * 2 * 2            // kvh + kvl (bf16)
                + (size_t)NH * 64 * 4;                 // ksum
    if (need <= ws_size) break;
    sch >>= 1;
  }
  float* part = (float*)d_ws;
  short* kvh  = (short*)((char*)d_ws + (size_t)NN * sch * 8 * KV_ELEMS * 4);
  short* kvl  = kvh + (size_t)NH * 4096;
  float* ksum = (float*)(kvl + (size_t)NH * 4096);

  hipLaunchKernelGGL(kv_partial_kernel, dim3(NN * sch), dim3(512), 0, stream,
                     K, V, part, sch);
  hipLaunchKernelGGL(kv_reduce_kernel, dim3(NH * 17), dim3(256), 0, stream,
                     part, kvh, kvl, ksum, sch);
  hipLaunchKernelGGL(attn_out_kernel, dim3(NN * CCH), dim3(512), 0, stream,
                     Q, kvh, kvl, ksum, out);
}